// Round 1
// baseline (635.724 us; speedup 1.0000x reference)
//
#include <hip/hip_runtime.h>

#define DM   1024
#define HN   16
#define DKH  64
#define SEQ  2048
#define BATCH 2

typedef __attribute__((ext_vector_type(8))) __bf16 bf16x8;
typedef __attribute__((ext_vector_type(4))) float  f32x4;

__device__ __forceinline__ unsigned short f2bf(float f) {
  union { float f; unsigned u; } v; v.f = f;
  unsigned u = v.u;
  u += 0x7FFFu + ((u >> 16) & 1u);   // round-to-nearest-even
  return (unsigned short)(u >> 16);
}

// ---------------- fp32 -> bf16 conversion ----------------
__global__ __launch_bounds__(256) void cvt_kernel(const float* __restrict__ in,
                                                  unsigned short* __restrict__ out,
                                                  int n4) {
  int i = blockIdx.x * 256 + threadIdx.x;
  if (i < n4) {
    float4 f = ((const float4*)in)[i];
    ushort4 o;
    o.x = f2bf(f.x); o.y = f2bf(f.y); o.z = f2bf(f.z); o.w = f2bf(f.w);
    ((ushort4*)out)[i] = o;
  }
}

// ---------------- GEMM: C = A @ W^T + bias ----------------
// A [M x K] row-major bf16, W [N x K] row-major bf16 (torch Linear weight).
// MODE 0: bf16 out [M x N]; MODE 1: bf16 out transposed per head
//         vpT[((b*HN+h)*DKH+dk)*SEQ + s]; MODE 2: fp32 out [M x N].
template <int MODE>
__global__ __launch_bounds__(256) void gemm_bt(
    const unsigned short* __restrict__ A,
    const unsigned short* __restrict__ W,
    const float* __restrict__ bias,
    float* __restrict__ outF,
    unsigned short* __restrict__ outB,
    int M, int N, int K) {
  const int wave = threadIdx.x >> 6;
  const int lane = threadIdx.x & 63;
  const int l15 = lane & 15, quad = lane >> 4;
  const int wr = wave >> 1, wc = wave & 1;
  const int bm = blockIdx.x * 64 + wr * 32;
  const int bn = blockIdx.y * 64 + wc * 32;

  f32x4 acc[2][2] = {};

  const unsigned short* a0p = A + (size_t)(bm + l15) * K + quad * 8;
  const unsigned short* a1p = a0p + (size_t)16 * K;
  const unsigned short* b0p = W + (size_t)(bn + l15) * K + quad * 8;
  const unsigned short* b1p = b0p + (size_t)16 * K;

  for (int k0 = 0; k0 < K; k0 += 32) {
    bf16x8 a0 = *(const bf16x8*)(a0p + k0);
    bf16x8 a1 = *(const bf16x8*)(a1p + k0);
    bf16x8 b0 = *(const bf16x8*)(b0p + k0);
    bf16x8 b1 = *(const bf16x8*)(b1p + k0);
    acc[0][0] = __builtin_amdgcn_mfma_f32_16x16x32_bf16(a0, b0, acc[0][0], 0, 0, 0);
    acc[0][1] = __builtin_amdgcn_mfma_f32_16x16x32_bf16(a0, b1, acc[0][1], 0, 0, 0);
    acc[1][0] = __builtin_amdgcn_mfma_f32_16x16x32_bf16(a1, b0, acc[1][0], 0, 0, 0);
    acc[1][1] = __builtin_amdgcn_mfma_f32_16x16x32_bf16(a1, b1, acc[1][1], 0, 0, 0);
  }

  for (int mt = 0; mt < 2; ++mt)
    for (int nt = 0; nt < 2; ++nt)
      for (int r = 0; r < 4; ++r) {
        int row = bm + mt * 16 + quad * 4 + r;
        int col = bn + nt * 16 + l15;
        float v = acc[mt][nt][r] + bias[col];
        if (MODE == 0) {
          outB[(size_t)row * N + col] = f2bf(v);
        } else if (MODE == 1) {
          int b = row >> 11, s = row & (SEQ - 1);
          int h = col >> 6, dk = col & (DKH - 1);
          outB[((size_t)((b * HN + h) * DKH + dk)) * SEQ + s] = f2bf(v);
        } else {
          outF[(size_t)row * N + col] = v;
        }
      }
}

// ---------------- flash attention ----------------
// grid (SEQ/64, BATCH*HN), block 256. wave w covers 16 query rows.
#define PLDS_STRIDE 56  // 112 B rows: 16B-aligned frag reads, 2-way bank alias (free)
__global__ __launch_bounds__(256) void attn_kernel(
    const unsigned short* __restrict__ qp,
    const unsigned short* __restrict__ kp,
    const unsigned short* __restrict__ vpT,
    const int* __restrict__ mask,
    unsigned short* __restrict__ ctx) {
  const int lane = threadIdx.x & 63;
  const int wave = threadIdx.x >> 6;
  const int l15 = lane & 15, quad = lane >> 4;
  const int bh = blockIdx.y;
  const int b = bh >> 4, h = bh & 15;
  const int q0 = blockIdx.x * 64 + wave * 16;  // query row base (within batch b)

  __shared__ __align__(16) unsigned short p_lds[4][16 * PLDS_STRIDE];

  const unsigned short* qbase =
      qp + ((size_t)(b * SEQ + q0 + l15)) * DM + h * DKH + quad * 8;
  bf16x8 aq0 = *(const bf16x8*)(qbase);
  bf16x8 aq1 = *(const bf16x8*)(qbase + 32);

  f32x4 o[4] = {};
  float mrow[4] = {-1e30f, -1e30f, -1e30f, -1e30f};
  float lrow[4] = {0.f, 0.f, 0.f, 0.f};

  const unsigned short* kbase = kp + ((size_t)b * SEQ) * DM + h * DKH + quad * 8;
  const unsigned short* vbase = vpT + ((size_t)bh * DKH) * SEQ + quad * 8;
  const int* mbase = mask + ((size_t)(b * SEQ + q0 + quad * 4)) * SEQ;

  for (int j0 = 0; j0 < SEQ; j0 += 32) {
    // S-tile [16 x 32] = Q(16x64) @ K_tile(32x64)^T
    f32x4 s[2] = {};
    {
      const unsigned short* k0p = kbase + (size_t)(j0 + l15) * DM;
      const unsigned short* k1p = kbase + (size_t)(j0 + 16 + l15) * DM;
      bf16x8 b00 = *(const bf16x8*)(k0p);
      bf16x8 b01 = *(const bf16x8*)(k0p + 32);
      bf16x8 b10 = *(const bf16x8*)(k1p);
      bf16x8 b11 = *(const bf16x8*)(k1p + 32);
      s[0] = __builtin_amdgcn_mfma_f32_16x16x32_bf16(aq0, b00, s[0], 0, 0, 0);
      s[0] = __builtin_amdgcn_mfma_f32_16x16x32_bf16(aq1, b01, s[0], 0, 0, 0);
      s[1] = __builtin_amdgcn_mfma_f32_16x16x32_bf16(aq0, b10, s[1], 0, 0, 0);
      s[1] = __builtin_amdgcn_mfma_f32_16x16x32_bf16(aq1, b11, s[1], 0, 0, 0);
    }
    // mask (replace with -10000) + scale 1/sqrt(64)
    float sv0[4], sv1[4];
    for (int r = 0; r < 4; ++r) {
      int m0 = mbase[(size_t)r * SEQ + j0 + l15];
      int m1 = mbase[(size_t)r * SEQ + j0 + 16 + l15];
      sv0[r] = m0 ? s[0][r] * 0.125f : -10000.0f;
      sv1[r] = m1 ? s[1][r] * 0.125f : -10000.0f;
    }
    // online softmax per row (rows live in 16 consecutive lanes)
    for (int r = 0; r < 4; ++r) {
      float vmax = fmaxf(sv0[r], sv1[r]);
      for (int off = 1; off < 16; off <<= 1)
        vmax = fmaxf(vmax, __shfl_xor(vmax, off, 64));
      float mnew = fmaxf(mrow[r], vmax);
      float alpha = __expf(mrow[r] - mnew);
      mrow[r] = mnew;
      float p0 = __expf(sv0[r] - mnew);
      float p1 = __expf(sv1[r] - mnew);
      float rs = p0 + p1;
      for (int off = 1; off < 16; off <<= 1)
        rs += __shfl_xor(rs, off, 64);
      lrow[r] = lrow[r] * alpha + rs;
      for (int t = 0; t < 4; ++t) o[t][r] *= alpha;
      p_lds[wave][(quad * 4 + r) * PLDS_STRIDE + l15] = f2bf(p0);
      p_lds[wave][(quad * 4 + r) * PLDS_STRIDE + 16 + l15] = f2bf(p1);
    }
    __syncthreads();  // C-layout -> A-layout transform through LDS
    bf16x8 ap = *(const bf16x8*)&p_lds[wave][l15 * PLDS_STRIDE + quad * 8];
    const unsigned short* vp0 = vbase + j0;
    for (int t = 0; t < 4; ++t) {
      bf16x8 bv = *(const bf16x8*)(vp0 + (size_t)(t * 16 + l15) * SEQ);
      o[t] = __builtin_amdgcn_mfma_f32_16x16x32_bf16(ap, bv, o[t], 0, 0, 0);
    }
    __syncthreads();  // protect LDS before next iteration's writes
  }
  // epilogue: normalize and store ctx (bf16, normal [token][dmodel] layout)
  for (int r = 0; r < 4; ++r) {
    float inv = 1.0f / lrow[r];
    for (int t = 0; t < 4; ++t) {
      float v = o[t][r] * inv;
      ctx[((size_t)(b * SEQ + q0 + quad * 4 + r)) * DM + h * DKH + t * 16 + l15] =
          f2bf(v);
    }
  }
}

// ---------------- launch ----------------
extern "C" void kernel_launch(void* const* d_in, const int* in_sizes, int n_in,
                              void* d_out, int out_size, void* d_ws, size_t ws_size,
                              hipStream_t stream) {
  const float* q    = (const float*)d_in[0];
  const float* k    = (const float*)d_in[1];
  const float* v    = (const float*)d_in[2];
  const int*   mask = (const int*)d_in[3];
  const float* Wq_w = (const float*)d_in[4];
  const float* Wq_b = (const float*)d_in[5];
  const float* Wk_w = (const float*)d_in[6];
  const float* Wk_b = (const float*)d_in[7];
  const float* Wv_w = (const float*)d_in[8];
  const float* Wv_b = (const float*)d_in[9];
  const float* Wo_w = (const float*)d_in[10];
  const float* Wo_b = (const float*)d_in[11];

  char* ws = (char*)d_ws;
  const size_t MB = 1024 * 1024;
  unsigned short* q_bf  = (unsigned short*)(ws + 0 * MB);
  unsigned short* k_bf  = (unsigned short*)(ws + 8 * MB);
  unsigned short* v_bf  = (unsigned short*)(ws + 16 * MB);
  unsigned short* Wq_bf = (unsigned short*)(ws + 24 * MB);
  unsigned short* Wk_bf = (unsigned short*)(ws + 26 * MB);
  unsigned short* Wv_bf = (unsigned short*)(ws + 28 * MB);
  unsigned short* Wo_bf = (unsigned short*)(ws + 30 * MB);
  unsigned short* qp    = (unsigned short*)(ws + 32 * MB);
  unsigned short* kp    = (unsigned short*)(ws + 40 * MB);
  unsigned short* vpT   = (unsigned short*)(ws + 48 * MB);
  unsigned short* ctx   = (unsigned short*)(ws + 56 * MB);

  const int M  = BATCH * SEQ;  // 4096
  const int nQ = M * DM;       // 4194304
  const int nW = DM * DM;      // 1048576

  cvt_kernel<<<nQ / 4 / 256, 256, 0, stream>>>(q, q_bf, nQ / 4);
  cvt_kernel<<<nQ / 4 / 256, 256, 0, stream>>>(k, k_bf, nQ / 4);
  cvt_kernel<<<nQ / 4 / 256, 256, 0, stream>>>(v, v_bf, nQ / 4);
  cvt_kernel<<<nW / 4 / 256, 256, 0, stream>>>(Wq_w, Wq_bf, nW / 4);
  cvt_kernel<<<nW / 4 / 256, 256, 0, stream>>>(Wk_w, Wk_bf, nW / 4);
  cvt_kernel<<<nW / 4 / 256, 256, 0, stream>>>(Wv_w, Wv_bf, nW / 4);
  cvt_kernel<<<nW / 4 / 256, 256, 0, stream>>>(Wo_w, Wo_bf, nW / 4);

  dim3 gblk(M / 64, DM / 64);  // (64, 16)
  gemm_bt<0><<<gblk, 256, 0, stream>>>(q_bf, Wq_bf, Wq_b, nullptr, qp, M, DM, DM);
  gemm_bt<0><<<gblk, 256, 0, stream>>>(k_bf, Wk_bf, Wk_b, nullptr, kp, M, DM, DM);
  gemm_bt<1><<<gblk, 256, 0, stream>>>(v_bf, Wv_bf, Wv_b, nullptr, vpT, M, DM, DM);

  dim3 ablk(SEQ / 64, BATCH * HN);  // (32, 32)
  attn_kernel<<<ablk, 256, 0, stream>>>(qp, kp, vpT, mask, ctx);

  gemm_bt<2><<<gblk, 256, 0, stream>>>(ctx, Wo_bf, Wo_b, (float*)d_out, nullptr, M, DM, DM);
}